// Round 18
// baseline (171.930 us; speedup 1.0000x reference)
//
#include <hip/hip_runtime.h>
#include <hip/hip_bf16.h>
#include <math.h>

#define B_ROWS 4096
#define D_DIM  256
#define N_TOT  8192            // 2B
#define E2     7.38905609893065f   // exp(2) = diagonal term of the row sum
#define NTILE  64              // 8192 / 128
#define NBLK   (NTILE * (NTILE + 1) / 2)   // 2080 upper-triangle tile pairs
#define NSLOT  128             // 2 sub-slots per tile-row (wave_n / wave_m split)
#define NRED   32              // last-32-ticket blocks run the reduce slices

typedef __attribute__((ext_vector_type(4))) float f32x4;

__device__ __forceinline__ void async_copy16(const void* gptr, void* lptr) {
    // NOTE: lptr is the WAVE-UNIFORM base; HW scatters lane*16 itself.
    __builtin_amdgcn_global_load_lds(
        (const __attribute__((address_space(1))) unsigned int*)gptr,
        (__attribute__((address_space(3))) unsigned int*)lptr,
        16 /*bytes*/, 0 /*offset*/, 0 /*aux*/);
}

// ---------------------------------------------------------------------------
// Kernel 1: wave-per-row L2-normalize query & pos -> fp8-e4m3 Z8[8192][256];
// per-row positive dot (f32-EXACT) to pospart[row]. (R16-proven, frozen.)
// Block 0 zeroes out[0] (loss accumulator) and cnt[0] (completion ticket) —
// kernel-boundary ordering makes both visible to simexp.
// ---------------------------------------------------------------------------
__global__ __launch_bounds__(256) void norm_kernel(
        const float* __restrict__ q, const float* __restrict__ p,
        unsigned char* __restrict__ Z8, float* __restrict__ pospart,
        unsigned int* __restrict__ cnt, float* __restrict__ out) {
    const int t    = threadIdx.x;
    const int wv   = t >> 6;
    const int lane = t & 63;
    const int row  = blockIdx.x * 4 + wv;        // 0..4095
    if (blockIdx.x == 0 && t == 0) { out[0] = 0.0f; cnt[0] = 0u; }

    const f32x4 qv = *(const f32x4*)(q + (size_t)row * D_DIM + lane * 4);
    const f32x4 pv = *(const f32x4*)(p + (size_t)row * D_DIM + lane * 4);
    float a = qv[0]*qv[0] + qv[1]*qv[1] + qv[2]*qv[2] + qv[3]*qv[3];
    float b = pv[0]*pv[0] + pv[1]*pv[1] + pv[2]*pv[2] + pv[3]*pv[3];
    float c = qv[0]*pv[0] + qv[1]*pv[1] + qv[2]*pv[2] + qv[3]*pv[3];
    #pragma unroll
    for (int off = 32; off > 0; off >>= 1) {
        a += __shfl_xor(a, off);
        b += __shfl_xor(b, off);
        c += __shfl_xor(c, off);
    }
    const float rq = 1.0f / fmaxf(sqrtf(a), 1e-12f);
    const float rp = 1.0f / fmaxf(sqrtf(b), 1e-12f);

    int zq = __builtin_amdgcn_cvt_pk_fp8_f32(qv[0] * rq, qv[1] * rq, 0, false);
    zq     = __builtin_amdgcn_cvt_pk_fp8_f32(qv[2] * rq, qv[3] * rq, zq, true);
    int zp = __builtin_amdgcn_cvt_pk_fp8_f32(pv[0] * rp, pv[1] * rp, 0, false);
    zp     = __builtin_amdgcn_cvt_pk_fp8_f32(pv[2] * rp, pv[3] * rp, zp, true);
    *(int*)(Z8 + (size_t)row * D_DIM + lane * 4)            = zq;
    *(int*)(Z8 + (size_t)(B_ROWS + row) * D_DIM + lane * 4) = zp;
    if (lane == 0) pospart[row] = c * rq * rp;
}

// ---------------------------------------------------------------------------
// Kernel 2: fused S = Z*Z^T (fp8 MFMA) + exp-rowsum partials + DEVICE-SIDE
// REDUCE VIA COMPLETION TICKET. GEMM interior frozen (R16/R17: BK=128,
// 2 drains, 32 KB LDS, XOR swizzle, (256,4)).
// THIS ROUND'S ONE CHANGE: after its stores, each block fences + takes a
// ticket from cnt. The last NRED=32 tickets spin (acquire, bounded) until
// cnt==NBLK, then each runs one 256-row reduce slice + loss atomicAdd —
// removing the reduce_kernel launch (~2.5 us, measured R10->R11) and
// overlapping the reduce with simexp's wind-down tail.
// Deadlock-free: ticket >= NBLK-32 implies 2048 blocks FINISHED, <=32 remain,
// 1024 CU slots exist -> spinners (<=32 slots) never starve the rest.
// Fence pattern (syncthreads -> threadfence -> ACQ_REL add / ACQUIRE spin)
// is byte-identical to R14's grid barrier, validated correct on this HW.
// Counter is a norm-zeroed workspace cell, NOT aliased with out (avoids
// float-corruption of the spin value).
// ---------------------------------------------------------------------------
__global__ __launch_bounds__(256, 4) void simexp_gemm(
        const unsigned char* __restrict__ Z8, float* __restrict__ bufP,
        const float* __restrict__ pospart, unsigned int* __restrict__ cnt,
        float* __restrict__ out) {
    __shared__ unsigned char As[128 * 128];   // 16 KB, row stride 128 B
    __shared__ unsigned char Bs[128 * 128];   // 16 KB
    __shared__ float red[4];
    __shared__ unsigned int ticket_s;
    const int tid    = threadIdx.x;
    const int lane   = tid & 63;
    const int wv     = tid >> 6;      // wave id 0..3
    const int wave_m = wv >> 1;       // 0..1  (row half)
    const int wave_n = wv & 1;        // 0..1  (col half)
    const int m16    = lane & 15;
    const int quad   = lane >> 4;

    // --- triangular decode: bid -> (bi <= bj) ---
    const int bid = blockIdx.x;
    int bi = (int)((129.0 - sqrt(129.0 * 129.0 - 8.0 * (double)bid)) * 0.5);
    while (bi > 0 && (bi * NTILE - bi * (bi - 1) / 2) > bid) --bi;
    while (((bi + 1) * NTILE - (bi + 1) * bi / 2) <= bid) ++bi;
    const int bj = bi + (bid - (bi * NTILE - bi * (bi - 1) / 2));
    const int rowBase = bi * 128;
    const int colBase = bj * 128;

    f32x4 acc[4][4];
    #pragma unroll
    for (int i = 0; i < 4; ++i)
        #pragma unroll
        for (int j = 0; j < 4; ++j) acc[i][j] = (f32x4){0.f, 0.f, 0.f, 0.f};

    // staging geometry: one instr = 64 lanes x 16B = 8 rows of 128 B (fp8
    // K-tile row = 128 B). lane l -> local row (l>>3), chunk slot (l&7);
    // LDS chunk c of row r holds global chunk c ^ (r&7). Z row stride 256 B.
    const int lrow = lane >> 3;
    const int lchk = lane & 7;
    unsigned int aoff[4], boff[4];
    #pragma unroll
    for (int pp = 0; pp < 4; ++pp) {
        const int r = wv * 32 + pp * 8 + lrow;          // local row 0..127
        const int g = lchk ^ (r & 7);                   // swizzled global chunk
        aoff[pp] = (unsigned int)((rowBase + r) * 256 + g * 16);
        boff[pp] = (unsigned int)((colBase + r) * 256 + g * 16);
    }

    for (int kt = 0; kt < 2; ++kt) {
        __syncthreads();   // previous iter's LDS reads done before overwrite
        #pragma unroll
        for (int pp = 0; pp < 4; ++pp) {
            async_copy16((const char*)Z8 + aoff[pp],
                         (char*)As + (wv * 32 + pp * 8) * 128);
            async_copy16((const char*)Z8 + boff[pp],
                         (char*)Bs + (wv * 32 + pp * 8) * 128);
            aoff[pp] += 128;   // next K-tile (128 fp8 = 128 B)
            boff[pp] += 128;
        }
        __syncthreads();   // drains vmcnt: staging complete

        #pragma unroll
        for (int kt2 = 0; kt2 < 4; ++kt2) {
            const int c  = (kt2 * 2 + (quad >> 1)) ^ (m16 & 7); // swizzled chunk
            const int o  = (quad & 1) * 8;
            const unsigned int abase =
                (unsigned int)((wave_m * 64 + m16) * 128 + c * 16 + o);
            const unsigned int bbase =
                (unsigned int)((wave_n * 64 + m16) * 128 + c * 16 + o);
            long af[4], bfr[4];
            #pragma unroll
            for (int mi = 0; mi < 4; ++mi)
                af[mi] = *(const long*)((const char*)As + abase + mi * 2048);
            #pragma unroll
            for (int ni = 0; ni < 4; ++ni)
                bfr[ni] = *(const long*)((const char*)Bs + bbase + ni * 2048);
            #pragma unroll
            for (int mi = 0; mi < 4; ++mi)
                #pragma unroll
                for (int ni = 0; ni < 4; ++ni)
                    acc[mi][ni] = __builtin_amdgcn_mfma_f32_16x16x32_fp8_fp8(
                        af[mi], bfr[ni], acc[mi][ni], 0, 0, 0);
        }
    }

    // --- epilogue: exp(2s) once; collision-free partial stores ---
    // C/D layout: col = lane&15, row = quad*4 + reg  [m89; dtype-independent].
    float cs[4] = {0.f, 0.f, 0.f, 0.f};
    float rs[4][4];
    #pragma unroll
    for (int mi = 0; mi < 4; ++mi)
        #pragma unroll
        for (int r = 0; r < 4; ++r) {
            float s = 0.f;
            #pragma unroll
            for (int ni = 0; ni < 4; ++ni) {
                const float e = __expf(2.0f * acc[mi][ni][r]);
                s += e;
                cs[ni] += e;
            }
            rs[mi][r] = s;
        }
    #pragma unroll
    for (int off = 1; off < 16; off <<= 1)
        #pragma unroll
        for (int mi = 0; mi < 4; ++mi)
            #pragma unroll
            for (int r = 0; r < 4; ++r)
                rs[mi][r] += __shfl_xor(rs[mi][r], off, 64);
    if (m16 == 0) {
        float* dst = bufP + (size_t)(2 * bj + wave_n) * N_TOT + rowBase;
        #pragma unroll
        for (int mi = 0; mi < 4; ++mi)
            #pragma unroll
            for (int r = 0; r < 4; ++r)
                dst[wave_m * 64 + mi * 16 + quad * 4 + r] = rs[mi][r];
    }
    if (bi != bj) {
        #pragma unroll
        for (int off = 16; off < 64; off <<= 1)
            #pragma unroll
            for (int ni = 0; ni < 4; ++ni)
                cs[ni] += __shfl_xor(cs[ni], off, 64);
        if (lane < 16) {
            float* dst = bufP + (size_t)(2 * bi + wave_m) * N_TOT + colBase;
            #pragma unroll
            for (int ni = 0; ni < 4; ++ni)
                dst[wave_n * 64 + ni * 16 + m16] = cs[ni];
        }
    }

    // --- completion ticket; last NRED tickets run the reduce slices ---
    __syncthreads();                  // all this block's stores retired
    if (tid == 0) {
        __threadfence();              // agent-scope release (XCD L2 writeback)
        ticket_s = __hip_atomic_fetch_add(cnt, 1u, __ATOMIC_ACQ_REL,
                                          __HIP_MEMORY_SCOPE_AGENT);
    }
    __syncthreads();
    const unsigned int ticket = ticket_s;
    if (ticket >= (unsigned)(NBLK - NRED)) {
        if (tid == 0) {
            unsigned int guard = 0;
            while (__hip_atomic_load(cnt, __ATOMIC_ACQUIRE,
                                     __HIP_MEMORY_SCOPE_AGENT) < (unsigned)NBLK
                   && ++guard < (1u << 27)) {
                __builtin_amdgcn_s_sleep(1);
            }
        }
        __syncthreads();              // all blocks' bufP stores now visible
        const int b = (int)(ticket - (unsigned)(NBLK - NRED));  // 0..31
        const int t = tid;
        const int r = b * 256 + t;                   // 0..8191
        float s[8] = {0.f, 0.f, 0.f, 0.f, 0.f, 0.f, 0.f, 0.f};
        #pragma unroll
        for (int k = 0; k < NSLOT; k += 8) {
            #pragma unroll
            for (int j = 0; j < 8; ++j)
                s[j] += bufP[(size_t)(k + j) * N_TOT + r];
        }
        const float denom = ((s[0] + s[1]) + (s[2] + s[3]))
                          + ((s[4] + s[5]) + (s[6] + s[7]));
        float contrib = logf(denom - E2);
        if (b < 16) contrib -= 4.0f * pospart[b * 256 + t];

        #pragma unroll
        for (int off = 32; off > 0; off >>= 1)
            contrib += __shfl_down(contrib, off);
        if ((t & 63) == 0) red[t >> 6] = contrib;
        __syncthreads();
        if (t == 0) {
            const float bs = (red[0] + red[1]) + (red[2] + red[3]);
            atomicAdd(out, bs / (float)N_TOT);
        }
    }
}

extern "C" void kernel_launch(void* const* d_in, const int* in_sizes, int n_in,
                              void* d_out, int out_size, void* d_ws, size_t ws_size,
                              hipStream_t stream) {
    const float* q = (const float*)d_in[0];
    const float* p = (const float*)d_in[1];
    // d_in[2] (neg) is normalized in the original but never used in the loss.
    float* out = (float*)d_out;

    // Workspace layout:
    //   Z8       fp8  [8192*256]  @ 0       (2 MiB)
    //   bufP     f32  [128*8192]  @ 2 MiB   (4 MiB)  exp-sum partials
    //   pospart  f32  [4096]      after bufP
    //   cnt      u32  [1]         after pospart (zeroed by norm_kernel)
    unsigned char* Z8 = (unsigned char*)d_ws;
    float* bufP        = (float*)((char*)d_ws + (size_t)N_TOT * D_DIM);
    float* pospart     = bufP + (size_t)NSLOT * N_TOT;
    unsigned int* cnt  = (unsigned int*)(pospart + B_ROWS);

    hipLaunchKernelGGL(norm_kernel, dim3(B_ROWS / 4), dim3(256), 0, stream,
                       q, p, Z8, pospart, cnt, out);
    hipLaunchKernelGGL(simexp_gemm, dim3(NBLK), dim3(256), 0, stream,
                       Z8, bufP, pospart, cnt, out);
}

// Round 19
// 96.026 us; speedup vs baseline: 1.7904x; 1.7904x over previous
//
#include <hip/hip_runtime.h>
#include <hip/hip_bf16.h>
#include <math.h>

#define B_ROWS 4096
#define D_DIM  256
#define N_TOT  8192            // 2B
#define E2     7.38905609893065f   // exp(2) = diagonal term of the row sum
#define NTILE  64              // 8192 / 128
#define NBLK   (NTILE * (NTILE + 1) / 2)   // 2080 upper-triangle tile pairs
#define NSLOT  128             // 2 sub-slots per tile-row (wave_n / wave_m split)

typedef __attribute__((ext_vector_type(4))) float f32x4;

__device__ __forceinline__ void async_copy16(const void* gptr, void* lptr) {
    // NOTE: lptr is the WAVE-UNIFORM base; HW scatters lane*16 itself.
    __builtin_amdgcn_global_load_lds(
        (const __attribute__((address_space(1))) unsigned int*)gptr,
        (__attribute__((address_space(3))) unsigned int*)lptr,
        16 /*bytes*/, 0 /*offset*/, 0 /*aux*/);
}

// ---------------------------------------------------------------------------
// Kernel 1: wave-per-row L2-normalize query & pos -> fp8-e4m3 Z8[8192][256];
// per-row positive dot (f32-EXACT) to pospart[row]. (R16/R17-proven, frozen.)
// Block 0 zeroes out[0] for the merged reduce's atomic accumulation.
// ---------------------------------------------------------------------------
__global__ __launch_bounds__(256) void norm_kernel(
        const float* __restrict__ q, const float* __restrict__ p,
        unsigned char* __restrict__ Z8, float* __restrict__ pospart,
        float* __restrict__ out) {
    const int t    = threadIdx.x;
    const int wv   = t >> 6;
    const int lane = t & 63;
    const int row  = blockIdx.x * 4 + wv;        // 0..4095
    if (blockIdx.x == 0 && t == 0) out[0] = 0.0f;

    const f32x4 qv = *(const f32x4*)(q + (size_t)row * D_DIM + lane * 4);
    const f32x4 pv = *(const f32x4*)(p + (size_t)row * D_DIM + lane * 4);
    float a = qv[0]*qv[0] + qv[1]*qv[1] + qv[2]*qv[2] + qv[3]*qv[3];
    float b = pv[0]*pv[0] + pv[1]*pv[1] + pv[2]*pv[2] + pv[3]*pv[3];
    float c = qv[0]*pv[0] + qv[1]*pv[1] + qv[2]*pv[2] + qv[3]*pv[3];
    #pragma unroll
    for (int off = 32; off > 0; off >>= 1) {
        a += __shfl_xor(a, off);
        b += __shfl_xor(b, off);
        c += __shfl_xor(c, off);
    }
    const float rq = 1.0f / fmaxf(sqrtf(a), 1e-12f);
    const float rp = 1.0f / fmaxf(sqrtf(b), 1e-12f);

    int zq = __builtin_amdgcn_cvt_pk_fp8_f32(qv[0] * rq, qv[1] * rq, 0, false);
    zq     = __builtin_amdgcn_cvt_pk_fp8_f32(qv[2] * rq, qv[3] * rq, zq, true);
    int zp = __builtin_amdgcn_cvt_pk_fp8_f32(pv[0] * rp, pv[1] * rp, 0, false);
    zp     = __builtin_amdgcn_cvt_pk_fp8_f32(pv[2] * rp, pv[3] * rp, zp, true);
    *(int*)(Z8 + (size_t)row * D_DIM + lane * 4)            = zq;
    *(int*)(Z8 + (size_t)(B_ROWS + row) * D_DIM + lane * 4) = zp;
    if (lane == 0) pospart[row] = c * rq * rp;
}

// ---------------------------------------------------------------------------
// Kernel 2: fused S = Z*Z^T (fp8 MFMA), upper-triangle tile pairs, epilogue
// exp-rowsum partials via collision-free stores. FROZEN at the R17-measured
// session best (96.8 us): BK=128 -> 2 K-iters = 2 vmcnt drains, 32 KB LDS,
// XOR source swizzle, __launch_bounds__(256,4) (fits naturally at fp8's
// ~124-reg footprint; 4 blocks/CU, TLP saturated per R17 null).
// Known: SQ_LDS_BANK_CONFLICT ~2.1M/dispatch from the b64 fragment reads —
// analysis says that's ~the 4-cycle wave64-b64 LDS floor (64 x 8 B = 512 B
// = 4 LDS clocks); fixing it requires breaking global_load_lds's linear-
// dest constraint. Left as-is.
// R18's completion-ticket reduce REVERTED: per-block device-scope
// __threadfence poisons L2 (simexp 33 -> 114 us) — launch gaps cannot be
// bought for less than their ~2.5 us cost on this hardware (3 mechanisms
// tried: coop API no-op R13, all-block spin R14, ticket fence R18).
//   row-partials of block (bi,bj) -> slot 2*bj+wave_n, rows of tile bi
//   col-partials of block (bi,bj) -> slot 2*bi+wave_m, cols of tile bj
// Every slot of bufP[128][8192] written exactly once; no init, no atomics.
// ---------------------------------------------------------------------------
__global__ __launch_bounds__(256, 4) void simexp_gemm(
        const unsigned char* __restrict__ Z8, float* __restrict__ bufP) {
    __shared__ unsigned char As[128 * 128];   // 16 KB, row stride 128 B
    __shared__ unsigned char Bs[128 * 128];   // 16 KB
    const int tid    = threadIdx.x;
    const int lane   = tid & 63;
    const int wv     = tid >> 6;      // wave id 0..3
    const int wave_m = wv >> 1;       // 0..1  (row half)
    const int wave_n = wv & 1;        // 0..1  (col half)
    const int m16    = lane & 15;
    const int quad   = lane >> 4;

    // --- triangular decode: bid -> (bi <= bj) ---
    const int bid = blockIdx.x;
    int bi = (int)((129.0 - sqrt(129.0 * 129.0 - 8.0 * (double)bid)) * 0.5);
    while (bi > 0 && (bi * NTILE - bi * (bi - 1) / 2) > bid) --bi;
    while (((bi + 1) * NTILE - (bi + 1) * bi / 2) <= bid) ++bi;
    const int bj = bi + (bid - (bi * NTILE - bi * (bi - 1) / 2));
    const int rowBase = bi * 128;
    const int colBase = bj * 128;

    f32x4 acc[4][4];
    #pragma unroll
    for (int i = 0; i < 4; ++i)
        #pragma unroll
        for (int j = 0; j < 4; ++j) acc[i][j] = (f32x4){0.f, 0.f, 0.f, 0.f};

    // staging geometry: one instr = 64 lanes x 16B = 8 rows of 128 B (fp8
    // K-tile row = 128 B). lane l -> local row (l>>3), chunk slot (l&7);
    // LDS chunk c of row r holds global chunk c ^ (r&7) (xor involution).
    // Z row stride = 256 B; kt advances +128 B.
    const int lrow = lane >> 3;
    const int lchk = lane & 7;
    unsigned int aoff[4], boff[4];
    #pragma unroll
    for (int pp = 0; pp < 4; ++pp) {
        const int r = wv * 32 + pp * 8 + lrow;          // local row 0..127
        const int g = lchk ^ (r & 7);                   // swizzled global chunk
        aoff[pp] = (unsigned int)((rowBase + r) * 256 + g * 16);
        boff[pp] = (unsigned int)((colBase + r) * 256 + g * 16);
    }

    for (int kt = 0; kt < 2; ++kt) {
        __syncthreads();   // previous iter's LDS reads done before overwrite
        #pragma unroll
        for (int pp = 0; pp < 4; ++pp) {
            async_copy16((const char*)Z8 + aoff[pp],
                         (char*)As + (wv * 32 + pp * 8) * 128);
            async_copy16((const char*)Z8 + boff[pp],
                         (char*)Bs + (wv * 32 + pp * 8) * 128);
            aoff[pp] += 128;   // next K-tile (128 fp8 = 128 B)
            boff[pp] += 128;
        }
        __syncthreads();   // drains vmcnt: staging complete

        #pragma unroll
        for (int kt2 = 0; kt2 < 4; ++kt2) {
            // lane (m16, quad) holds k = kt2*32 + quad*8 .. +7 of its row.
            // global chunk gc = kt2*2 + (quad>>1); within-chunk byte (quad&1)*8
            const int c  = (kt2 * 2 + (quad >> 1)) ^ (m16 & 7); // swizzled chunk
            const int o  = (quad & 1) * 8;
            const unsigned int abase =
                (unsigned int)((wave_m * 64 + m16) * 128 + c * 16 + o);
            const unsigned int bbase =
                (unsigned int)((wave_n * 64 + m16) * 128 + c * 16 + o);
            long af[4], bfr[4];
            #pragma unroll
            for (int mi = 0; mi < 4; ++mi)
                af[mi] = *(const long*)((const char*)As + abase + mi * 2048);
            #pragma unroll
            for (int ni = 0; ni < 4; ++ni)
                bfr[ni] = *(const long*)((const char*)Bs + bbase + ni * 2048);
            #pragma unroll
            for (int mi = 0; mi < 4; ++mi)
                #pragma unroll
                for (int ni = 0; ni < 4; ++ni)
                    acc[mi][ni] = __builtin_amdgcn_mfma_f32_16x16x32_fp8_fp8(
                        af[mi], bfr[ni], acc[mi][ni], 0, 0, 0);
        }
    }

    // --- epilogue: exp(2s) once; row partials and col partials ---
    // C/D layout: col = lane&15, row = quad*4 + reg  [m89; dtype-independent].
    float cs[4] = {0.f, 0.f, 0.f, 0.f};
    float rs[4][4];
    #pragma unroll
    for (int mi = 0; mi < 4; ++mi)
        #pragma unroll
        for (int r = 0; r < 4; ++r) {
            float s = 0.f;
            #pragma unroll
            for (int ni = 0; ni < 4; ++ni) {
                const float e = __expf(2.0f * acc[mi][ni][r]);
                s += e;
                cs[ni] += e;
            }
            rs[mi][r] = s;
        }
    // row sums: reduce across the 16 columns (lanes sharing a quad)
    #pragma unroll
    for (int off = 1; off < 16; off <<= 1)
        #pragma unroll
        for (int mi = 0; mi < 4; ++mi)
            #pragma unroll
            for (int r = 0; r < 4; ++r)
                rs[mi][r] += __shfl_xor(rs[mi][r], off, 64);
    if (m16 == 0) {
        float* dst = bufP + (size_t)(2 * bj + wave_n) * N_TOT + rowBase;
        #pragma unroll
        for (int mi = 0; mi < 4; ++mi)
            #pragma unroll
            for (int r = 0; r < 4; ++r)
                dst[wave_m * 64 + mi * 16 + quad * 4 + r] = rs[mi][r];
    }
    // col sums: reduce across the 4 quads (rows) -> symmetric contribution
    if (bi != bj) {
        #pragma unroll
        for (int off = 16; off < 64; off <<= 1)
            #pragma unroll
            for (int ni = 0; ni < 4; ++ni)
                cs[ni] += __shfl_xor(cs[ni], off, 64);
        if (lane < 16) {
            float* dst = bufP + (size_t)(2 * bi + wave_m) * N_TOT + colBase;
            #pragma unroll
            for (int ni = 0; ni < 4; ++ni)
                dst[wave_n * 64 + ni * 16 + m16] = cs[ni];
        }
    }
}

// ---------------------------------------------------------------------------
// Kernel 2b (merged reduce + finalize, R11-proven, frozen): block b of 32
// owns rows r=b*256+t; 8 accumulator chains; thread 0 atomicAdds
// block_sum/8192 into out[0].
// ---------------------------------------------------------------------------
__global__ __launch_bounds__(256) void reduce_kernel(
        const float* __restrict__ bufP, const float* __restrict__ pospart,
        float* __restrict__ out) {
    const int b = blockIdx.x;                    // 0..31
    const int t = threadIdx.x;                   // 0..255
    const int r = b * 256 + t;                   // 0..8191
    float s[8] = {0.f, 0.f, 0.f, 0.f, 0.f, 0.f, 0.f, 0.f};
    #pragma unroll
    for (int k = 0; k < NSLOT; k += 8) {
        #pragma unroll
        for (int j = 0; j < 8; ++j)
            s[j] += bufP[(size_t)(k + j) * N_TOT + r];
    }
    const float denom = ((s[0] + s[1]) + (s[2] + s[3]))
                      + ((s[4] + s[5]) + (s[6] + s[7]));
    float contrib = logf(denom - E2);
    if (b < 16) contrib -= 4.0f * pospart[b * 256 + t];

    #pragma unroll
    for (int off = 32; off > 0; off >>= 1)
        contrib += __shfl_down(contrib, off);
    __shared__ float red[4];
    if ((t & 63) == 0) red[t >> 6] = contrib;
    __syncthreads();
    if (t == 0) {
        const float bs = (red[0] + red[1]) + (red[2] + red[3]);
        atomicAdd(out, bs / (float)N_TOT);
    }
}

extern "C" void kernel_launch(void* const* d_in, const int* in_sizes, int n_in,
                              void* d_out, int out_size, void* d_ws, size_t ws_size,
                              hipStream_t stream) {
    const float* q = (const float*)d_in[0];
    const float* p = (const float*)d_in[1];
    // d_in[2] (neg) is normalized in the original but never used in the loss.
    float* out = (float*)d_out;

    // Workspace layout:
    //   Z8       fp8  [8192*256]  @ 0       (2 MiB)
    //   bufP     f32  [128*8192]  @ 2 MiB   (4 MiB)  exp-sum partials
    //   pospart  f32  [4096]      after bufP
    unsigned char* Z8 = (unsigned char*)d_ws;
    float* bufP     = (float*)((char*)d_ws + (size_t)N_TOT * D_DIM);
    float* pospart  = bufP + (size_t)NSLOT * N_TOT;

    hipLaunchKernelGGL(norm_kernel, dim3(B_ROWS / 4), dim3(256), 0, stream,
                       q, p, Z8, pospart, out);
    hipLaunchKernelGGL(simexp_gemm, dim3(NBLK), dim3(256), 0, stream, Z8, bufP);
    hipLaunchKernelGGL(reduce_kernel, dim3(32), dim3(256), 0, stream,
                       bufP, pospart, out);
}